// Round 9
// baseline (319.266 us; speedup 1.0000x reference)
//
#include <hip/hip_runtime.h>

#define MDIM 8192
#define NDIM 4096
#define KDIM 4096

typedef __attribute__((ext_vector_type(8))) short short8;
typedef __attribute__((ext_vector_type(4))) float f32x4;
typedef __attribute__((ext_vector_type(16))) float f32x16;
typedef unsigned short u16;
typedef unsigned int u32;

__device__ __forceinline__ u16 f2bf(float f) {
  return __builtin_bit_cast(u16, static_cast<__bf16>(f));
}

// ---------------- prepass 1: x f32 -> bf16 ----------------
__global__ __launch_bounds__(256) void cvt_x_kernel(const float* __restrict__ x,
                                                    u16* __restrict__ xb, int n8) {
  const int stride = gridDim.x * 256;
  for (int u = blockIdx.x * 256 + threadIdx.x; u < n8; u += stride) {
    const float* p = x + (size_t)u * 8;
    const f32x4 a = *(const f32x4*)p;
    const f32x4 b = *(const f32x4*)(p + 4);
    short8 v;
#pragma unroll
    for (int j = 0; j < 4; ++j) {
      v[j]     = (short)f2bf(a[j]);
      v[4 + j] = (short)f2bf(b[j]);
    }
    *(short8*)(xb + (size_t)u * 8) = v;
  }
}

// ---------------- prepass 2: dequant -> MFMA-fragment-linear Bp ----------------
// unit index = nblk*16384 + kblk*64 + lane; holds W[nblk*32+(lane&31)][kblk*16+(lane>>5)*8+e]
__global__ __launch_bounds__(256) void dequant_w_kernel(const int* __restrict__ qw,
                                                        const int* __restrict__ qz,
                                                        const float* __restrict__ sc,
                                                        u16* __restrict__ wt) {
  const int g = blockIdx.x * 256 + threadIdx.x;  // 0..524287
  const int n = g & (NDIM - 1);
  const int kp0 = (g >> 12) * 4;
  const float s = sc[n];
  const int zw = qz[n >> 3];
  const int zp1 = ((zw >> ((n & 7) * 4)) & 0xF) + 1;
  const float sz = -(float)zp1 * s;
  const int nblk = n >> 5;
  const int lnlo = n & 31;
#pragma unroll
  for (int i = 0; i < 4; ++i) {
    const int kp = kp0 + i;
    const int w = qw[(size_t)kp * NDIM + n];
    short8 v;
#pragma unroll
    for (int j = 0; j < 8; ++j)
      v[j] = (short)f2bf(fmaf((float)((w >> (4 * j)) & 0xF), s, sz));
    const int kblk = kp >> 1;
    const int lane = ((kp & 1) << 5) + lnlo;
    const size_t unit = (size_t)nblk * 16384 + (size_t)kblk * 64 + lane;
    *(short8*)(wt + unit * 8) = v;
  }
}

// ---------------- main GEMM: 256x256, 32x32x16, waves 64x128, B k-chunk time-share ----
#define BAR()    __builtin_amdgcn_s_barrier()
#define FENCE()  __builtin_amdgcn_sched_barrier(0)
#define VM12()   asm volatile("s_waitcnt vmcnt(12)" ::: "memory")
#define PRIO1()  __builtin_amdgcn_s_setprio(1)
#define PRIO0()  __builtin_amdgcn_s_setprio(0)

// stage full A-tile (256x64) for K-tile T into buffer BUF (4 glds, 16B/lane)
#define STGA(BUF, T) do {                                                     \
    _Pragma("unroll")                                                         \
    for (int r_ = 0; r_ < 4; ++r_) {                                          \
      __builtin_amdgcn_global_load_lds(                                       \
        (const __attribute__((address_space(1))) void*)                       \
          (pA4[r_] + (size_t)(T) * 64),                                       \
        (__attribute__((address_space(3))) void*)                             \
          (AsB + (BUF) * 32768 + r_ * 8192 + tid * 16), 16, 0, 0);            \
    }                                                                         \
  } while (0)

// load one B half-chunk: 8 frags (fn 0..3 x kw {KW0,KW0+1}) into SET
#define LDBH(SET, T, KW0) do {                                                \
    _Pragma("unroll")                                                         \
    for (int fn_ = 0; fn_ < 4; ++fn_)                                         \
      _Pragma("unroll")                                                       \
      for (int j_ = 0; j_ < 2; ++j_)                                          \
        SET[fn_ * 2 + j_] = *(const short8*)(pB0 + (size_t)fn_ * 262144 +     \
            (size_t)(T) * 4096 + ((KW0) + j_) * 1024);                        \
  } while (0)

// half-phase compute: 2 kw x (2 A-reads + 8 MFMA)
#define MFH(BUF, SET, KW0) do {                                               \
    _Pragma("unroll")                                                         \
    for (int j_ = 0; j_ < 2; ++j_) {                                          \
      const char* b_ = AsB + (BUF) * 32768 + aaddr[(KW0) + j_];               \
      short8 aq0 = *(const short8*)(b_);                                      \
      short8 aq1 = *(const short8*)(b_ + 4096);                               \
      _Pragma("unroll")                                                       \
      for (int fn_ = 0; fn_ < 4; ++fn_) {                                     \
        acc[0][fn_] = __builtin_amdgcn_mfma_f32_32x32x16_bf16(                \
            aq0, SET[fn_ * 2 + j_], acc[0][fn_], 0, 0, 0);                    \
        acc[1][fn_] = __builtin_amdgcn_mfma_f32_32x32x16_bf16(                \
            aq1, SET[fn_ * 2 + j_], acc[1][fn_], 0, 0, 0);                    \
      }                                                                       \
    }                                                                         \
  } while (0)

// one K-tile phase, one barrier
#define PHASE(T, BUF, BUFS) do {                                              \
    const int tn_ = ((T) + 1) & 63;                                           \
    const int ts_ = ((T) + 3) & 63;                                           \
    LDBH(bY, (T), 2); FENCE();                                                \
    PRIO1(); MFH(BUF, bX, 0); PRIO0();                                        \
    LDBH(bX, tn_, 0); STGA(BUFS, ts_); FENCE();                               \
    PRIO1(); MFH(BUF, bY, 2); PRIO0();                                        \
    VM12(); FENCE(); BAR(); FENCE();                                          \
  } while (0)

__global__ __launch_bounds__(512, 2) void qgemm_bf16_w2(const u16* __restrict__ A,
                                                        const u16* __restrict__ Bp,
                                                        float* __restrict__ out) {
  __shared__ __align__(16) char AsB[4 * 32768];  // 4-deep A tiles [256][64] bf16, swizzled

  const int tid  = threadIdx.x;
  const int lane = tid & 63;
  const int wave = tid >> 6;
  const int wrow = wave >> 1;  // 0..3 -> 64 output rows each
  const int wcol = wave & 1;   // 0..1 -> 128 output cols each

  const int bid = blockIdx.x;
  const int sb = bid >> 4, li = bid & 15;
  const int mb = (sb & 7) * 4 + (li & 3);    // 0..31
  const int nb = (sb >> 3) * 4 + (li >> 2);  // 0..15
  const int m0 = mb * 256, n0 = nb * 256;

  // A staging bases (involution: LDS slot u holds global unit u^(row&7))
  const u16* pA4[4];
#pragma unroll
  for (int r = 0; r < 4; ++r) {
    const int row = r * 64 + (tid >> 3);
    const int su = (tid & 7) ^ ((tid >> 3) & 7);
    pA4[r] = A + (size_t)(m0 + row) * KDIM + su * 8;
  }

  // B base: fragment-linear, this wave's 4-nblk stripe (128 cols)
  const char* pB0 = (const char*)Bp +
      ((size_t)(n0 >> 5) + wcol * 4) * 262144 + lane * 16;

  // A fragment addresses: row = wrow*64 + fm*32 + (l&31); slot = (kw*2+hi)^(l&7)
  const int hi = lane >> 5;
  const int lx = lane & 7;
  const int rowbase = (wrow * 64 + (lane & 31)) * 128;
  int aaddr[4];
#pragma unroll
  for (int kw = 0; kw < 4; ++kw)
    aaddr[kw] = rowbase + (((kw * 2 + hi) ^ lx) << 4);

  f32x16 acc[2][4];
#pragma unroll
  for (int i = 0; i < 2; ++i)
#pragma unroll
    for (int j = 0; j < 4; ++j)
      acc[i][j] = (f32x16)(0.f);

  short8 bX[8], bY[8];  // k01 / k23 chunk register sets (static indexing)

  // ---- prologue: A(0),A(1),A(2) staged; B(0,k01) in flight ----
  STGA(0, 0);
  STGA(1, 1);
  STGA(2, 2);
  LDBH(bX, 0, 0);
  asm volatile("s_waitcnt vmcnt(8)" ::: "memory");  // forces STGA(0..2)
  BAR(); FENCE();

  // ---- main loop: 16 iters x 4 K-tiles ----
  for (int it = 0; it < 16; ++it) {
    const int tb = it * 4;
    PHASE(tb + 0, 0, 3);
    PHASE(tb + 1, 1, 0);
    PHASE(tb + 2, 2, 1);
    PHASE(tb + 3, 3, 2);
  }

  asm volatile("s_waitcnt vmcnt(0)" ::: "memory");  // drain wrapped dead stages

  // ---- epilogue: 32x32 C/D: col=lane&31, row=(reg&3)+8*(reg>>2)+4*(lane>>5) ----
#pragma unroll
  for (int fm = 0; fm < 2; ++fm) {
#pragma unroll
    for (int fn = 0; fn < 4; ++fn) {
      const f32x16 c = acc[fm][fn];
      const int gc = n0 + wcol * 128 + fn * 32 + (lane & 31);
      const int gr0 = m0 + wrow * 64 + fm * 32 + hi * 4;
#pragma unroll
      for (int rg = 0; rg < 16; ++rg) {
        const int gr = gr0 + (rg & 3) + 8 * (rg >> 2);
        out[(size_t)gr * NDIM + gc] = c[rg];
      }
    }
  }
}

// ---------------- fallback: fused f32-input kernel (r3, proven) ----------------
#define BM 128
#define BN 128
#define BK 64
#define NKT (KDIM / BK)
#define LDA 72
__global__ __launch_bounds__(256) void qgemm_fused_f32(
    const float* __restrict__ x, const int* __restrict__ qweight,
    const int* __restrict__ qzeros, const float* __restrict__ scales,
    float* __restrict__ out) {
  __shared__ __align__(16) short As[BM * LDA];
  __shared__ __align__(16) short Bs[BN * LDA];

  const int tid = threadIdx.x;
  const int lane = tid & 63;
  const int wave = tid >> 6;
  const int wr = wave >> 1, wc = wave & 1;
  const int bid = blockIdx.x;
  const int sb = bid >> 4, li = bid & 15;
  const int mb = (sb & 15) * 4 + (li & 3);
  const int nb = (sb >> 4) * 4 + (li >> 2);
  const int m0 = mb * BM, n0 = nb * BN;

  const int ncol = tid & 127;
  const int kp_base = (tid >> 7) * 4;
  const int n_g = n0 + ncol;
  const float s = scales[n_g];
  const int zw = qzeros[n_g >> 3];
  const int zp1 = ((zw >> ((n_g & 7) * 4)) & 0xF) + 1;
  const float sz = -(float)zp1 * s;

  const int arow0 = tid >> 3;
  const int acol = (tid & 7) * 8;
  const int* qwp = qweight + (size_t)kp_base * NDIM + n_g;

  f32x4 af[8];
  {
    const float* xf = x + (size_t)(m0 + arow0) * KDIM + acol;
#pragma unroll
    for (int g = 0; g < 4; ++g) {
      af[2 * g]     = *(const f32x4*)(xf + (size_t)g * 32 * KDIM);
      af[2 * g + 1] = *(const f32x4*)(xf + (size_t)g * 32 * KDIM + 4);
    }
  }
  int qw0 = qwp[0], qw1 = qwp[NDIM], qw2 = qwp[2 * NDIM], qw3 = qwp[3 * NDIM];

  f32x4 acc[4][4];
#pragma unroll
  for (int i = 0; i < 4; ++i)
#pragma unroll
    for (int j = 0; j < 4; ++j)
      acc[i][j] = (f32x4)(0.f);

  const int lr = lane & 15, kh = lane >> 4;

  for (int kt = 0; kt < NKT; ++kt) {
    __syncthreads();
#pragma unroll
    for (int g = 0; g < 4; ++g) {
      short8 v;
#pragma unroll
      for (int j = 0; j < 4; ++j) {
        v[j]     = (short)f2bf(af[2 * g][j]);
        v[4 + j] = (short)f2bf(af[2 * g + 1][j]);
      }
      *(short8*)&As[(arow0 + g * 32) * LDA + acol] = v;
    }
    {
      const int qq[4] = {qw0, qw1, qw2, qw3};
#pragma unroll
      for (int r = 0; r < 4; ++r) {
        const int w = qq[r];
        short8 v;
#pragma unroll
        for (int j = 0; j < 8; ++j)
          v[j] = (short)f2bf(fmaf((float)((w >> (4 * j)) & 0xF), s, sz));
        *(short8*)&Bs[ncol * LDA + (kp_base + r) * 8] = v;
      }
    }
    if (kt + 1 < NKT) {
      const float* xp = x + (size_t)(m0 + arow0) * KDIM + (size_t)(kt + 1) * BK + acol;
#pragma unroll
      for (int g = 0; g < 4; ++g) {
        af[2 * g]     = *(const f32x4*)(xp + (size_t)g * 32 * KDIM);
        af[2 * g + 1] = *(const f32x4*)(xp + (size_t)g * 32 * KDIM + 4);
      }
      const int* p = qwp + (size_t)(kt + 1) * 8 * NDIM;
      qw0 = p[0]; qw1 = p[NDIM]; qw2 = p[2 * NDIM]; qw3 = p[3 * NDIM];
    }
    __syncthreads();
#pragma unroll
    for (int ks = 0; ks < 2; ++ks) {
      const int kb = (ks * 4 + kh) * 8;
      short8 a[4], bb[4];
#pragma unroll
      for (int mf = 0; mf < 4; ++mf)
        a[mf] = *(const short8*)&As[(wr * 64 + mf * 16 + lr) * LDA + kb];
#pragma unroll
      for (int nf = 0; nf < 4; ++nf)
        bb[nf] = *(const short8*)&Bs[(wc * 64 + nf * 16 + lr) * LDA + kb];
#pragma unroll
      for (int mf = 0; mf < 4; ++mf)
#pragma unroll
        for (int nf = 0; nf < 4; ++nf)
          acc[mf][nf] = __builtin_amdgcn_mfma_f32_16x16x32_bf16(a[mf], bb[nf], acc[mf][nf], 0, 0, 0);
    }
  }
#pragma unroll
  for (int mf = 0; mf < 4; ++mf)
#pragma unroll
    for (int nf = 0; nf < 4; ++nf) {
      const f32x4 c = acc[mf][nf];
      const int gc = n0 + wc * 64 + nf * 16 + lr;
#pragma unroll
      for (int rg = 0; rg < 4; ++rg)
        out[(size_t)(m0 + wr * 64 + mf * 16 + kh * 4 + rg) * NDIM + gc] = c[rg];
    }
}

extern "C" void kernel_launch(void* const* d_in, const int* in_sizes, int n_in,
                              void* d_out, int out_size, void* d_ws, size_t ws_size,
                              hipStream_t stream) {
  const float* x      = (const float*)d_in[0];  // fp16 ref stored as f32 on device
  const int* qweight  = (const int*)d_in[2];    // [K/8][N] int32
  const int* qzeros   = (const int*)d_in[3];    // [1][N/8] int32
  const float* scales = (const float*)d_in[4];  // fp16 ref stored as f32
  float* out = (float*)d_out;

  const size_t xb_bytes = (size_t)MDIM * KDIM * 2;  // 64 MB
  const size_t wt_bytes = (size_t)NDIM * KDIM * 2;  // 32 MB

  if (ws_size >= xb_bytes + wt_bytes) {
    u16* xb = (u16*)d_ws;
    u16* wt = (u16*)((char*)d_ws + xb_bytes);
    cvt_x_kernel<<<2048, 256, 0, stream>>>(x, xb, MDIM * KDIM / 8);
    dequant_w_kernel<<<2048, 256, 0, stream>>>(qweight, qzeros, scales, wt);
    const int grid = (MDIM / 256) * (NDIM / 256);  // 512
    qgemm_bf16_w2<<<grid, 512, 0, stream>>>(xb, wt, out);
  } else {
    const int grid = (MDIM / BM) * (NDIM / BN);  // 2048
    qgemm_fused_f32<<<grid, 256, 0, stream>>>(x, qweight, qzeros, scales, out);
  }
}